// Round 1
// baseline (283.130 us; speedup 1.0000x reference)
//
#include <hip/hip_runtime.h>
#include <cstdint>
#include <cstddef>

// SSMLayer: LN -> (D,D) GEMM -> (D,192) proj GEMM -> chunked parallel scan
//           -> fused output GEMM  out = CH@(W_so@W_out) + xp@(D.*W_out) + b_out + x
// All GEMMs: bf16 MFMA 16x16x32, fp32 accumulate. Scan in fp32.
// M = 32768 rows, D = 512, N = 64.

typedef unsigned short bf16_t;
typedef __attribute__((ext_vector_type(8))) short bh8;
typedef __attribute__((ext_vector_type(4))) float f4;

#define M_ROWS 32768

// float -> bf16 RNE via bit trick (no dependence on hip_bf16 API)
__device__ __forceinline__ unsigned short f2bf(float f) {
  union { float f; unsigned int u; } c; c.f = f;
  unsigned int u = c.u;
  return (unsigned short)((u + 0x7FFFu + ((u >> 16) & 1u)) >> 16);
}

// async 16B global->LDS (wave-uniform LDS base + lane*16)
__device__ __forceinline__ void async_cp16(void* lds, const void* g) {
  __builtin_amdgcn_global_load_lds((const __attribute__((address_space(1))) void*)g,
                                   (__attribute__((address_space(3))) void*)lds, 16, 0, 0);
}

// ---------------- prep kernels (per-call weight massage; tiny) ----------------
// Wt_in[n][k] = W_in[k][n] (bf16); Wcat[n][k] = {W_xs|W_B|W_C}[k][n] (pad n to 256);
// W1f[k][n] = sum_j W_so[k][j]*W_out[j][n]; Abar/Apow.
__global__ __launch_bounds__(256) void prep_a(
    const float* __restrict__ W_in, const float* __restrict__ W_xs,
    const float* __restrict__ W_B,  const float* __restrict__ W_C,
    const float* __restrict__ W_so, const float* __restrict__ W_out,
    const float* __restrict__ A_log,
    bf16_t* __restrict__ Wt_in, bf16_t* __restrict__ Wcat,
    float* __restrict__ W1f, float* __restrict__ Abar, float* __restrict__ Apow) {
  int i = blockIdx.x * 256 + threadIdx.x;
  if (i < 512 * 512) {                      // transpose W_in
    int n = i >> 9, k = i & 511;
    Wt_in[n * 512 + k] = f2bf(W_in[k * 512 + n]);
    return;
  }
  i -= 512 * 512;
  if (i < 256 * 512) {                      // concat+transpose xs|B|C, zero-pad
    int n = i >> 9, k = i & 511;
    float v = 0.f;
    if (n < 64)       v = W_xs[k * 64 + n];
    else if (n < 128) v = W_B[k * 64 + n - 64];
    else if (n < 192) v = W_C[k * 64 + n - 128];
    Wcat[n * 512 + k] = f2bf(v);
    return;
  }
  i -= 256 * 512;
  if (i < 64 * 512) {                       // W1 = W_so @ W_out (fp32)
    int k = i >> 9, n = i & 511;
    float s = 0.f;
    for (int j = 0; j < 512; ++j) s = fmaf(W_so[k * 512 + j], W_out[j * 512 + n], s);
    W1f[k * 512 + n] = s;
    return;
  }
  i -= 64 * 512;
  if (i < 64) {
    float a = __expf(A_log[i]);
    Abar[i] = __expf(-a);
    Apow[i] = __expf(-a * 64.f);            // A_bar^64 (chunk length)
  }
}

// Wcat2[n][k]: k<64 -> W1[k][n]; k>=64 -> D_skip[k-64]*W_out[k-64][n]  (bf16, K=576)
__global__ __launch_bounds__(256) void prep_b(
    const float* __restrict__ W_out, const float* __restrict__ D_skip,
    const float* __restrict__ W1f, bf16_t* __restrict__ Wcat2) {
  int i = blockIdx.x * 256 + threadIdx.x;
  if (i >= 512 * 576) return;
  int n = i / 576, k = i - n * 576;
  float v = (k < 64) ? W1f[k * 512 + n]
                     : D_skip[k - 64] * W_out[(size_t)(k - 64) * 512 + n];
  Wcat2[i] = f2bf(v);
}

// ---------------- LayerNorm: one wave per row, output bf16 ----------------
__global__ __launch_bounds__(256) void ln_kernel(
    const float* __restrict__ x, const float* __restrict__ gamma,
    const float* __restrict__ beta, bf16_t* __restrict__ xn) {
  const int row = blockIdx.x * 4 + (threadIdx.x >> 6);
  const int lane = threadIdx.x & 63;
  const float* xr = x + (size_t)row * 512 + lane * 8;
  float4 v0 = *(const float4*)xr;
  float4 v1 = *(const float4*)(xr + 4);
  float s  = v0.x + v0.y + v0.z + v0.w + v1.x + v1.y + v1.z + v1.w;
  float sq = v0.x*v0.x + v0.y*v0.y + v0.z*v0.z + v0.w*v0.w
           + v1.x*v1.x + v1.y*v1.y + v1.z*v1.z + v1.w*v1.w;
  #pragma unroll
  for (int off = 32; off > 0; off >>= 1) {
    s  += __shfl_xor(s, off, 64);
    sq += __shfl_xor(sq, off, 64);
  }
  const float mu  = s * (1.0f / 512.0f);
  const float var = sq * (1.0f / 512.0f) - mu * mu;
  const float rs  = rsqrtf(var + 1e-3f);
  float4 g0 = *(const float4*)(gamma + lane * 8);
  float4 g1 = *(const float4*)(gamma + lane * 8 + 4);
  float4 b0 = *(const float4*)(beta + lane * 8);
  float4 b1 = *(const float4*)(beta + lane * 8 + 4);
  bh8 ov;
  ov[0] = (short)f2bf((v0.x - mu) * rs * g0.x + b0.x);
  ov[1] = (short)f2bf((v0.y - mu) * rs * g0.y + b0.y);
  ov[2] = (short)f2bf((v0.z - mu) * rs * g0.z + b0.z);
  ov[3] = (short)f2bf((v0.w - mu) * rs * g0.w + b0.w);
  ov[4] = (short)f2bf((v1.x - mu) * rs * g1.x + b1.x);
  ov[5] = (short)f2bf((v1.y - mu) * rs * g1.y + b1.y);
  ov[6] = (short)f2bf((v1.z - mu) * rs * g1.z + b1.z);
  ov[7] = (short)f2bf((v1.w - mu) * rs * g1.w + b1.w);
  *(bh8*)(xn + (size_t)row * 512 + lane * 8) = ov;
}

// ---------------- MFMA GEMM: 128x128 tile, BK=64, 4 waves of 64x64 ----------------
// MODE 1: xp_bf16 = xn @ Wt_in^T + b_in            (outbf)
// MODE 2: proj f32[:,0:192] = xp @ Wcat^T (+bias)  (outf, N grid = 256 padded)
// MODE 3: out = [CH|xp] @ Wcat2^T + b_out + x      (outf, K=576)
template <int MODE>
__global__ __launch_bounds__(256, 2) void gemm_mfma(
    const bf16_t* __restrict__ A0, const bf16_t* __restrict__ A1,
    const bf16_t* __restrict__ Wt, int K,
    bf16_t* __restrict__ outbf, float* __restrict__ outf,
    const float* __restrict__ bias0, const float* __restrict__ bias1,
    const float* __restrict__ resid) {
  __shared__ __align__(16) bf16_t As[128 * 64];
  __shared__ __align__(16) bf16_t Bs[128 * 64];
  const int tid = threadIdx.x;
  const int wave = tid >> 6, lane = tid & 63;
  const int quad = lane >> 4, l16 = lane & 15;
  const int wm = (wave >> 1) * 64, wn = (wave & 1) * 64;
  const int mb = blockIdx.x, nb = blockIdx.y;

  f4 acc[4][4];
  #pragma unroll
  for (int i = 0; i < 4; ++i)
    #pragma unroll
    for (int j = 0; j < 4; ++j) acc[i][j] = (f4){0.f, 0.f, 0.f, 0.f};

  const int nkt = K >> 6;
  for (int kt = 0; kt < nkt; ++kt) {
    const int k0 = kt << 6;
    const bf16_t* Ap; int lda, kk;
    if (MODE == 3) {
      if (kt == 0) { Ap = A0; lda = 64;  kk = 0; }        // CH tile (K 0..63)
      else         { Ap = A1; lda = 512; kk = k0 - 64; }  // xp tile
    } else { Ap = A0; lda = K; kk = k0; }

    __syncthreads();  // prior readers done before overwrite
    // stage A: 1024 16B chunks, XOR-swizzled: LDS slot lc holds global chunk lc^(row&7)
    #pragma unroll
    for (int i = 0; i < 4; ++i) {
      const int base = (wave * 4 + i) * 64;   // wave-uniform chunk base
      const int cid = base + lane;
      const int row = cid >> 3;
      const int g = (cid & 7) ^ (row & 7);
      async_cp16((char*)As + base * 16,
                 Ap + (size_t)(mb * 128 + row) * lda + kk + g * 8);
    }
    #pragma unroll
    for (int i = 0; i < 4; ++i) {
      const int base = (wave * 4 + i) * 64;
      const int cid = base + lane;
      const int row = cid >> 3;
      const int g = (cid & 7) ^ (row & 7);
      async_cp16((char*)Bs + base * 16,
                 Wt + (size_t)(nb * 128 + row) * K + k0 + g * 8);
    }
    __syncthreads();  // vmcnt(0) drained by barrier

    #pragma unroll
    for (int ks = 0; ks < 2; ++ks) {
      const int gb = ks * 4 + quad;  // k-chunk for this MFMA k-step
      bh8 af[4], bfv[4];
      #pragma unroll
      for (int im = 0; im < 4; ++im) {
        const int row = wm + im * 16 + l16;
        af[im] = *(const bh8*)((const char*)As + row * 128 + ((gb ^ (row & 7)) * 16));
      }
      #pragma unroll
      for (int in_ = 0; in_ < 4; ++in_) {
        const int row = wn + in_ * 16 + l16;
        bfv[in_] = *(const bh8*)((const char*)Bs + row * 128 + ((gb ^ (row & 7)) * 16));
      }
      #pragma unroll
      for (int im = 0; im < 4; ++im)
        #pragma unroll
        for (int in_ = 0; in_ < 4; ++in_)
          acc[im][in_] = __builtin_amdgcn_mfma_f32_16x16x32_bf16(af[im], bfv[in_],
                                                                 acc[im][in_], 0, 0, 0);
    }
  }

  // epilogue: C/D layout col=lane&15, row=quad*4+reg  [m89-verified]
  #pragma unroll
  for (int im = 0; im < 4; ++im) {
    #pragma unroll
    for (int in_ = 0; in_ < 4; ++in_) {
      #pragma unroll
      for (int r = 0; r < 4; ++r) {
        const int row = mb * 128 + wm + im * 16 + quad * 4 + r;
        const int col = nb * 128 + wn + in_ * 16 + l16;
        float v = acc[im][in_][r];
        if (MODE == 1) {
          outbf[(size_t)row * 512 + col] = f2bf(v + bias0[col]);
        } else if (MODE == 2) {
          if (col < 192) {
            float b = (col < 64) ? 0.f : ((col < 128) ? bias0[col - 64] : bias1[col - 128]);
            outf[(size_t)row * 192 + col] = v + b;
          }
        } else {
          outf[(size_t)row * 512 + col] = v + bias0[col] + resid[(size_t)row * 512 + col];
        }
      }
    }
  }
}

// ---------------- chunked scan: 64 chunks x 64 steps, 512 chains ----------------
// phase A: local carries (h starting from 0)
__global__ __launch_bounds__(64) void scan_chunk(
    const float* __restrict__ proj, const float* __restrict__ Abar,
    float* __restrict__ carry) {
  const int b = blockIdx.x >> 6, c = blockIdx.x & 63, n = threadIdx.x;
  const float A = Abar[n];
  const float* p = proj + ((size_t)b * 4096 + c * 64) * 192;
  float h = 0.f;
  for (int i = 0; i < 64; ++i) {
    float xs = p[i * 192 + n];
    float bm = p[i * 192 + 64 + n];
    h = fmaf(A, h, xs * bm);
  }
  carry[(b * 64 + c) * 64 + n] = h;
}

// phase B: combine carries across chunks (sequential over 64, parallel over 512 chains)
__global__ __launch_bounds__(512) void scan_carry(
    const float* __restrict__ carry, const float* __restrict__ Apow,
    float* __restrict__ cin) {
  const int b = threadIdx.x >> 6, n = threadIdx.x & 63;
  const float Ap = Apow[n];
  float h = 0.f;
  for (int c = 0; c < 64; ++c) {
    cin[(b * 64 + c) * 64 + n] = h;
    h = fmaf(Ap, h, carry[(b * 64 + c) * 64 + n]);
  }
}

// phase C: replay with true carry-in, emit CH = C * h (bf16)
__global__ __launch_bounds__(64) void scan_apply(
    const float* __restrict__ proj, const float* __restrict__ Abar,
    const float* __restrict__ cin, bf16_t* __restrict__ CH) {
  const int b = blockIdx.x >> 6, c = blockIdx.x & 63, n = threadIdx.x;
  const float A = Abar[n];
  const float* p = proj + ((size_t)b * 4096 + c * 64) * 192;
  bf16_t* o = CH + ((size_t)b * 4096 + c * 64) * 64;
  float h = cin[(b * 64 + c) * 64 + n];
  for (int i = 0; i < 64; ++i) {
    float xs = p[i * 192 + n];
    float bm = p[i * 192 + 64 + n];
    float cv = p[i * 192 + 128 + n];
    h = fmaf(A, h, xs * bm);
    o[i * 64 + n] = f2bf(cv * h);
  }
}

// ---------------- launch ----------------
extern "C" void kernel_launch(void* const* d_in, const int* in_sizes, int n_in,
                              void* d_out, int out_size, void* d_ws, size_t ws_size,
                              hipStream_t stream) {
  const float* x      = (const float*)d_in[0];
  const float* ln_g   = (const float*)d_in[1];
  const float* ln_b   = (const float*)d_in[2];
  const float* W_in   = (const float*)d_in[3];
  const float* b_in   = (const float*)d_in[4];
  const float* W_xs   = (const float*)d_in[5];
  const float* W_B    = (const float*)d_in[6];
  const float* b_B    = (const float*)d_in[7];
  const float* W_C    = (const float*)d_in[8];
  const float* b_C    = (const float*)d_in[9];
  const float* A_log  = (const float*)d_in[10];
  const float* D_skip = (const float*)d_in[11];
  const float* W_so   = (const float*)d_in[12];
  const float* W_out  = (const float*)d_in[13];
  const float* b_out  = (const float*)d_in[14];
  float* out = (float*)d_out;

  // workspace carve (~98.5 MB total)
  char* w = (char*)d_ws;
  auto carve = [&](size_t bytes) {
    char* p = w; w += (bytes + 255) & ~(size_t)255; return p;
  };
  bf16_t* xn    = (bf16_t*)carve((size_t)M_ROWS * 512 * 2);
  bf16_t* xp    = (bf16_t*)carve((size_t)M_ROWS * 512 * 2);
  float*  proj  = (float*)carve((size_t)M_ROWS * 192 * 4);
  bf16_t* CH    = (bf16_t*)carve((size_t)M_ROWS * 64 * 2);
  float*  carry = (float*)carve(8 * 64 * 64 * 4);
  float*  cin   = (float*)carve(8 * 64 * 64 * 4);
  bf16_t* Wt_in = (bf16_t*)carve(512 * 512 * 2);
  bf16_t* Wcat  = (bf16_t*)carve(256 * 512 * 2);
  float*  W1f   = (float*)carve(64 * 512 * 4);
  bf16_t* Wcat2 = (bf16_t*)carve(512 * 576 * 2);
  float*  Abar  = (float*)carve(256);
  float*  Apow  = (float*)carve(256);

  prep_a<<<1665, 256, 0, stream>>>(W_in, W_xs, W_B, W_C, W_so, W_out, A_log,
                                   Wt_in, Wcat, W1f, Abar, Apow);
  prep_b<<<1152, 256, 0, stream>>>(W_out, D_skip, W1f, Wcat2);
  ln_kernel<<<8192, 256, 0, stream>>>(x, ln_g, ln_b, xn);
  gemm_mfma<1><<<dim3(256, 4), 256, 0, stream>>>(xn, nullptr, Wt_in, 512,
                                                 xp, nullptr, b_in, nullptr, nullptr);
  gemm_mfma<2><<<dim3(256, 2), 256, 0, stream>>>(xp, nullptr, Wcat, 512,
                                                 nullptr, proj, b_B, b_C, nullptr);
  scan_chunk<<<512, 64, 0, stream>>>(proj, Abar, carry);
  scan_carry<<<1, 512, 0, stream>>>(carry, Apow, cin);
  scan_apply<<<512, 64, 0, stream>>>(proj, Abar, cin, CH);
  gemm_mfma<3><<<dim3(256, 4), 256, 0, stream>>>(CH, xp, Wcat2, 576,
                                                 nullptr, out, b_out, nullptr, x);
}